// Round 4
// baseline (678.873 us; speedup 1.0000x reference)
//
#include <hip/hip_runtime.h>
#include <hip/hip_bf16.h>

typedef __attribute__((ext_vector_type(8))) short short8;
typedef __attribute__((ext_vector_type(4))) float f32x4;

#define GLOAD_LDS16(gp, lp)                                                      \
  __builtin_amdgcn_global_load_lds(                                              \
      (const __attribute__((address_space(1))) void*)(gp),                       \
      (__attribute__((address_space(3))) void*)(lp), 16, 0, 0)

#define SBAR() asm volatile("s_barrier" ::: "memory")
#define VMC(n)                                                                   \
  do {                                                                           \
    asm volatile("s_waitcnt vmcnt(" #n ")" ::: "memory");                        \
    __builtin_amdgcn_sched_barrier(0);                                           \
  } while (0)

__device__ __forceinline__ unsigned short f2bf_rne(float f) {
  union { float f; unsigned int u; } v; v.f = f;
  unsigned int u = v.u;
  u += 0x7fffu + ((u >> 16) & 1u);
  return (unsigned short)(u >> 16);
}

// ---------------------------------------------------------------- convert ----
__global__ void cvt_f32_bf16(const float* __restrict__ src,
                             unsigned short* __restrict__ dst, int n8) {
  int i = blockIdx.x * blockDim.x + threadIdx.x;
  int stride = gridDim.x * blockDim.x;
  const f32x4* s4 = (const f32x4*)src;
  short8* d8 = (short8*)dst;
  for (; i < n8; i += stride) {
    f32x4 a = s4[2 * i], b = s4[2 * i + 1];
    short8 o;
    o[0] = (short)f2bf_rne(a[0]); o[1] = (short)f2bf_rne(a[1]);
    o[2] = (short)f2bf_rne(a[2]); o[3] = (short)f2bf_rne(a[3]);
    o[4] = (short)f2bf_rne(b[0]); o[5] = (short)f2bf_rne(b[1]);
    o[6] = (short)f2bf_rne(b[2]); o[7] = (short)f2bf_rne(b[3]);
    d8[i] = o;
  }
}

// ------------------------------------------------- T = mask * 2 * (x @ A^T) ---
__global__ __launch_bounds__(256) void lora_t_kernel(
    const unsigned short* __restrict__ xb,
    const unsigned short* __restrict__ Ab,
    const int* __restrict__ offs,
    unsigned short* __restrict__ T)
{
  __shared__ unsigned short xs[64 * 64];
  __shared__ unsigned short as_[32 * 64];
  const int t = threadIdx.x;
  const int m0 = blockIdx.x * 64;
  const int l = t & 63, w = t >> 6;
  const int lr = l & 15, lk = (l >> 4) * 8;
  const int arow = t >> 3, acol = (t & 7) * 8;
  f32x4 acc0 = {0, 0, 0, 0}, acc1 = {0, 0, 0, 0};
  for (int kt = 0; kt < 64; ++kt) {
    __syncthreads();
    const int kof = kt * 64 + acol;
    GLOAD_LDS16(xb + (size_t)(m0 + arow) * 4096 + kof,      (char*)xs + (arow * 64 + acol) * 2);
    GLOAD_LDS16(xb + (size_t)(m0 + 32 + arow) * 4096 + kof, (char*)xs + ((32 + arow) * 64 + acol) * 2);
    GLOAD_LDS16(Ab + (size_t)arow * 4096 + kof,             (char*)as_ + (arow * 64 + acol) * 2);
    __syncthreads();
#pragma unroll
    for (int kk = 0; kk < 2; ++kk) {
      short8 a  = *(const short8*)&xs[(w * 16 + lr) * 64 + kk * 32 + lk];
      short8 b0 = *(const short8*)&as_[lr * 64 + kk * 32 + lk];
      short8 b1 = *(const short8*)&as_[(16 + lr) * 64 + kk * 32 + lk];
      acc0 = __builtin_amdgcn_mfma_f32_16x16x32_bf16(a, b0, acc0, 0, 0, 0);
      acc1 = __builtin_amdgcn_mfma_f32_16x16x32_bf16(a, b1, acc1, 0, 0, 0);
    }
  }
  const int rowb = (l >> 4) * 4;
#pragma unroll
  for (int j = 0; j < 4; ++j) {
    int m = m0 + w * 16 + rowb + j;
    int bb = m >> 12, s = m & 4095;
    int kcut = offs[bb]; if (kcut > 4096) kcut = 4096;
    bool keep = s >= 4096 - kcut;
    T[(size_t)m * 32 + lr]      = keep ? f2bf_rne(2.0f * acc0[j]) : (unsigned short)0;
    T[(size_t)m * 32 + 16 + lr] = keep ? f2bf_rne(2.0f * acc1[j]) : (unsigned short)0;
  }
}

// ------------------------------------------------------------- main GEMM -----
// 256x256 tile, BK=64, 2 LDS slots x {A,B} x 2 halves (128 rows x 64 els, 16KB).
// 8 waves; wave w -> A-quadrant wqr=w>>2 (fixed), 64-row sub pr=(w>>1)&1,
// 64-col sub pc=w&1; acc[qc][4][4] covers cols of both B-halves.
// 8 phases/iter (2 K-tiles x 2 B-halves x 2 kk): 8 ds_read_b128 + 1 half stage
// (2 gload_lds) + 16 MFMA + vmcnt(4) per phase.  LDS swizzle (m201 st_16x32):
// chunk ^= ((row>>2)&1)<<1, inverse-permuted global SOURCE + same XOR on reads.
__global__ __launch_bounds__(512, 2) void gemm_kernel(
    const unsigned short* __restrict__ xb,   // [16384][4096] bf16
    const unsigned short* __restrict__ Wb,   // [4096][4096]  bf16
    const unsigned short* __restrict__ Tm,   // [16384][32]   bf16 (mask+scale)
    const unsigned short* __restrict__ Bwb,  // [4096][32]    bf16
    const float* __restrict__ bias,          // [4096]
    float* __restrict__ out)                 // [16384][4096] f32
{
  constexpr int K = 4096;
  extern __shared__ char smem[];             // 128 KiB

  const int bid = blockIdx.x;
  const int swz = (bid & 7) * 128 + (bid >> 3);
  const int m0 = (swz >> 4) * 256;
  const int n0 = (swz & 15) * 256;

  const int t = threadIdx.x;
  const int l = t & 63, w = t >> 6;
  const int wqr = w >> 2;
  const int pr = (w >> 1) & 1;
  const int pc = w & 1;
  const int lr = l & 15, hi = l >> 4;
  const int pl2 = ((lr >> 2) & 1) << 1;      // read-side swizzle XOR
  const int e0 = (hi ^ pl2) * 8;             // element offset of 16B chunk

  // staging: thread t stages 16B chunk c=q*512+t (q=0,1) of a 16KB half.
  // linear LDS dest; source chunk = (t&7) ^ ((row>>2)&1)<<1, row=(q*512+t)>>3.
  const int srow = t >> 3;
  const int schunk = ((t & 7) ^ (((t >> 5) & 1) << 1)) * 8;
  const unsigned short* pA0 = xb + (size_t)(m0 + srow) * K + schunk;
  const unsigned short* pA1 = xb + (size_t)(m0 + 128 + srow) * K + schunk;
  const unsigned short* pB0 = Wb + (size_t)(n0 + srow) * K + schunk;
  const unsigned short* pB1 = Wb + (size_t)(n0 + 128 + srow) * K + schunk;
  unsigned short* sm = (unsigned short*)smem;
  const int ldst = t * 16;

#define STG(PTR, SLOT, ISB, HALF, KT)                                           \
  do {                                                                          \
    const unsigned short* g_ = (PTR) + (KT) * 64;                               \
    char* d_ = smem + (SLOT) * 65536 + (ISB) * 32768 + (HALF) * 16384 + ldst;   \
    GLOAD_LDS16(g_, d_);                                                        \
    GLOAD_LDS16(g_ + (size_t)64 * K, d_ + 8192);                                \
  } while (0)

  f32x4 acc[2][4][4];

  // --- LoRA prestep: register-direct (L2-resident), initializes acc ---
  {
    const unsigned short* tp = Tm + (size_t)(m0 + wqr * 128 + pr * 64 + lr) * 32 + hi * 8;
    short8 la[4];
#pragma unroll
    for (int i = 0; i < 4; ++i) la[i] = *(const short8*)(tp + i * 512);
    short8 lb[2][4];
#pragma unroll
    for (int qc = 0; qc < 2; ++qc)
#pragma unroll
      for (int j = 0; j < 4; ++j)
        lb[qc][j] = *(const short8*)(Bwb + (size_t)(n0 + qc * 128 + pc * 64 + j * 16 + lr) * 32 + hi * 8);
#pragma unroll
    for (int qc = 0; qc < 2; ++qc)
#pragma unroll
      for (int i = 0; i < 4; ++i)
#pragma unroll
        for (int j = 0; j < 4; ++j)
          acc[qc][i][j] = __builtin_amdgcn_mfma_f32_16x16x32_bf16(
              la[i], lb[qc][j], (f32x4){0.f, 0.f, 0.f, 0.f}, 0, 0, 0);
  }

  // prologue: s0 all 4 halves @kt0, s1.B0 @kt1
  STG(pA0, 0, 0, 0, 0);
  STG(pA1, 0, 0, 1, 0);
  STG(pB0, 0, 1, 0, 0);
  STG(pB1, 0, 1, 1, 0);
  STG(pB0, 1, 1, 0, 1);
  VMC(2);
  SBAR();

#define PHASE(SLOT, QC, KK, STG_STMT, WAIT_STMT)                                \
  {                                                                             \
    const unsigned short* Ah = sm + (SLOT) * 32768 + wqr * 8192;                \
    const unsigned short* Bh = sm + (SLOT) * 32768 + 16384 + (QC) * 8192;       \
    const int ek = e0 + (KK) * 32;                                              \
    short8 afr[4], bfr[4];                                                      \
    _Pragma("unroll")                                                           \
    for (int i = 0; i < 4; ++i)                                                 \
      afr[i] = *(const short8*)(Ah + (pr * 64 + i * 16 + lr) * 64 + ek);        \
    _Pragma("unroll")                                                           \
    for (int j = 0; j < 4; ++j)                                                 \
      bfr[j] = *(const short8*)(Bh + (pc * 64 + j * 16 + lr) * 64 + ek);        \
    STG_STMT;                                                                   \
    SBAR();                                                                     \
    __builtin_amdgcn_s_setprio(1);                                              \
    _Pragma("unroll")                                                           \
    for (int i = 0; i < 4; ++i)                                                 \
      _Pragma("unroll")                                                         \
      for (int j = 0; j < 4; ++j)                                               \
        acc[QC][i][j] = __builtin_amdgcn_mfma_f32_16x16x32_bf16(                \
            afr[i], bfr[j], acc[QC][i][j], 0, 0, 0);                            \
    __builtin_amdgcn_s_setprio(0);                                              \
    WAIT_STMT;                                                                  \
    SBAR();                                                                     \
  }

  // 64 K-tiles = 32 iters; iters 0..30 full, iter 31 tail-drains.
  for (int I = 0; I < 31; ++I) {
    const int a = 2 * I;
    PHASE(0, 0, 0, STG(pA0, 1, 0, 0, a + 1), VMC(4));  // stage s1.A0 @b
    PHASE(0, 0, 1, STG(pA1, 1, 0, 1, a + 1), VMC(4));  // s1.A1 @b
    PHASE(0, 1, 0, STG(pB1, 1, 1, 1, a + 1), VMC(4));  // s1.B1 @b
    PHASE(0, 1, 1, STG(pB0, 0, 1, 0, a + 2), VMC(4));  // s0.B0 @a+2
    PHASE(1, 0, 0, STG(pA0, 0, 0, 0, a + 2), VMC(4));  // s0.A0 @a+2
    PHASE(1, 0, 1, STG(pA1, 0, 0, 1, a + 2), VMC(4));  // s0.A1 @a+2
    PHASE(1, 1, 0, STG(pB1, 0, 1, 1, a + 2), VMC(4));  // s0.B1 @a+2
    PHASE(1, 1, 1, STG(pB0, 1, 1, 0, a + 3), VMC(4));  // s1.B0 @b+2
  }
  // tail iter: a=62, b=63
  PHASE(0, 0, 0, STG(pA0, 1, 0, 0, 63), VMC(4));
  PHASE(0, 0, 1, STG(pA1, 1, 0, 1, 63), VMC(4));
  PHASE(0, 1, 0, STG(pB1, 1, 1, 1, 63), VMC(4));
  PHASE(0, 1, 1, ((void)0), VMC(2));
  PHASE(1, 0, 0, ((void)0), VMC(0));
  PHASE(1, 0, 1, ((void)0), ((void)0));
  PHASE(1, 1, 0, ((void)0), ((void)0));
  PHASE(1, 1, 1, ((void)0), ((void)0));
#undef PHASE
#undef STG

  // epilogue: bias + store (C/D map: col=lr -> N, row=hi*4+e -> M)
  float bv[2][4];
#pragma unroll
  for (int qc = 0; qc < 2; ++qc)
#pragma unroll
    for (int j = 0; j < 4; ++j)
      bv[qc][j] = bias[n0 + qc * 128 + pc * 64 + j * 16 + lr];
  const int rowb = hi * 4;
#pragma unroll
  for (int qc = 0; qc < 2; ++qc)
#pragma unroll
    for (int i = 0; i < 4; ++i)
#pragma unroll
      for (int e = 0; e < 4; ++e) {
        int row = m0 + wqr * 128 + pr * 64 + i * 16 + rowb + e;
        float* orow = out + (size_t)row * 4096 + n0 + qc * 128 + pc * 64;
#pragma unroll
        for (int j = 0; j < 4; ++j) orow[j * 16 + lr] = acc[qc][i][j][e] + bv[qc][j];
      }
}

// ----------------------------------------------------------------- launch ----
extern "C" void kernel_launch(void* const* d_in, const int* in_sizes, int n_in,
                              void* d_out, int out_size, void* d_ws, size_t ws_size,
                              hipStream_t stream) {
  const float* x   = (const float*)d_in[0];
  const int* offs  = (const int*)d_in[1];
  const float* W   = (const float*)d_in[2];
  const float* b   = (const float*)d_in[3];
  const float* A   = (const float*)d_in[4];
  const float* Bw  = (const float*)d_in[5];
  float* out = (float*)d_out;

  char* ws = (char*)d_ws;
  unsigned short* xb  = (unsigned short*)ws;
  unsigned short* Wb  = (unsigned short*)(ws + 134217728);
  unsigned short* Ab  = (unsigned short*)(ws + 167772160);
  unsigned short* Bwb = (unsigned short*)(ws + 168034304);
  unsigned short* T   = (unsigned short*)(ws + 168296448);

  hipFuncSetAttribute((const void*)gemm_kernel,
                      hipFuncAttributeMaxDynamicSharedMemorySize, 131072);

  cvt_f32_bf16<<<2048, 256, 0, stream>>>(x, xb, 67108864 / 8);
  cvt_f32_bf16<<<2048, 256, 0, stream>>>(W, Wb, 16777216 / 8);
  cvt_f32_bf16<<<64, 256, 0, stream>>>(A, Ab, 131072 / 8);
  cvt_f32_bf16<<<64, 256, 0, stream>>>(Bw, Bwb, 131072 / 8);
  lora_t_kernel<<<256, 256, 0, stream>>>(xb, Ab, offs, T);
  gemm_kernel<<<1024, 512, 131072, stream>>>(xb, Wb, T, Bwb, b, out);
}

// Round 5
// 632.397 us; speedup vs baseline: 1.0735x; 1.0735x over previous
//
#include <hip/hip_runtime.h>
#include <hip/hip_bf16.h>

typedef __attribute__((ext_vector_type(8))) short short8;
typedef __attribute__((ext_vector_type(4))) float f32x4;

#define GLOAD_LDS16(gp, lp)                                                      \
  __builtin_amdgcn_global_load_lds(                                              \
      (const __attribute__((address_space(1))) void*)(gp),                       \
      (__attribute__((address_space(3))) void*)(lp), 16, 0, 0)

#define SBAR() asm volatile("s_barrier" ::: "memory")
#define VMC(n)                                                                   \
  do {                                                                           \
    asm volatile("s_waitcnt vmcnt(" #n ")" ::: "memory");                        \
    __builtin_amdgcn_sched_barrier(0);                                           \
  } while (0)

__device__ __forceinline__ unsigned short f2bf_rne(float f) {
  union { float f; unsigned int u; } v; v.f = f;
  unsigned int u = v.u;
  u += 0x7fffu + ((u >> 16) & 1u);
  return (unsigned short)(u >> 16);
}

// ---------------------------------------------------------------- convert ----
__global__ void cvt_f32_bf16(const float* __restrict__ src,
                             unsigned short* __restrict__ dst, int n8) {
  int i = blockIdx.x * blockDim.x + threadIdx.x;
  int stride = gridDim.x * blockDim.x;
  const f32x4* s4 = (const f32x4*)src;
  short8* d8 = (short8*)dst;
  for (; i < n8; i += stride) {
    f32x4 a = s4[2 * i], b = s4[2 * i + 1];
    short8 o;
    o[0] = (short)f2bf_rne(a[0]); o[1] = (short)f2bf_rne(a[1]);
    o[2] = (short)f2bf_rne(a[2]); o[3] = (short)f2bf_rne(a[3]);
    o[4] = (short)f2bf_rne(b[0]); o[5] = (short)f2bf_rne(b[1]);
    o[6] = (short)f2bf_rne(b[2]); o[7] = (short)f2bf_rne(b[3]);
    d8[i] = o;
  }
}

// ------------------------------------------------- T = mask * 2 * (x @ A^T) ---
__global__ __launch_bounds__(256) void lora_t_kernel(
    const unsigned short* __restrict__ xb,
    const unsigned short* __restrict__ Ab,
    const int* __restrict__ offs,
    unsigned short* __restrict__ T)
{
  __shared__ unsigned short xs[64 * 64];
  __shared__ unsigned short as_[32 * 64];
  const int t = threadIdx.x;
  const int m0 = blockIdx.x * 64;
  const int l = t & 63, w = t >> 6;
  const int lr = l & 15, lk = (l >> 4) * 8;
  const int arow = t >> 3, acol = (t & 7) * 8;
  f32x4 acc0 = {0, 0, 0, 0}, acc1 = {0, 0, 0, 0};
  for (int kt = 0; kt < 64; ++kt) {
    __syncthreads();
    const int kof = kt * 64 + acol;
    GLOAD_LDS16(xb + (size_t)(m0 + arow) * 4096 + kof,      (char*)xs + (arow * 64 + acol) * 2);
    GLOAD_LDS16(xb + (size_t)(m0 + 32 + arow) * 4096 + kof, (char*)xs + ((32 + arow) * 64 + acol) * 2);
    GLOAD_LDS16(Ab + (size_t)arow * 4096 + kof,             (char*)as_ + (arow * 64 + acol) * 2);
    __syncthreads();
#pragma unroll
    for (int kk = 0; kk < 2; ++kk) {
      short8 a  = *(const short8*)&xs[(w * 16 + lr) * 64 + kk * 32 + lk];
      short8 b0 = *(const short8*)&as_[lr * 64 + kk * 32 + lk];
      short8 b1 = *(const short8*)&as_[(16 + lr) * 64 + kk * 32 + lk];
      acc0 = __builtin_amdgcn_mfma_f32_16x16x32_bf16(a, b0, acc0, 0, 0, 0);
      acc1 = __builtin_amdgcn_mfma_f32_16x16x32_bf16(a, b1, acc1, 0, 0, 0);
    }
  }
  const int rowb = (l >> 4) * 4;
#pragma unroll
  for (int j = 0; j < 4; ++j) {
    int m = m0 + w * 16 + rowb + j;
    int bb = m >> 12, s = m & 4095;
    int kcut = offs[bb]; if (kcut > 4096) kcut = 4096;
    bool keep = s >= 4096 - kcut;
    T[(size_t)m * 32 + lr]      = keep ? f2bf_rne(2.0f * acc0[j]) : (unsigned short)0;
    T[(size_t)m * 32 + 16 + lr] = keep ? f2bf_rne(2.0f * acc1[j]) : (unsigned short)0;
  }
}

// ------------------------------------------------------------- main GEMM -----
// 256x256 tile, BK=64, 2 LDS slots x {A,B} x 2 halves (128 rows x 64 els, 16KB).
// 8 waves (wqr = A-half, pr = 64-row sub, pc = 64-col sub); acc[qc][4][4].
// Phase order per slot: (qc0,kk0)[read A+B0], (qc1,kk0)[read B1, reuse A],
// (qc0,kk1)[read A+B0], (qc1,kk1)[read B1] -> 24 b128 reads / 64 MFMA / K-tile.
// Swizzle: phys 16B-chunk = logical ^ ((row>>2)&1)<<2 (chunk BIT 2 -> 8 chunk
// positions x 8 lanes = 8 words/bank floor). Linear gload_lds dest; inverse-
// permuted global source; same XOR on read element offset (rule #21).
__global__ __launch_bounds__(512, 2) void gemm_kernel(
    const unsigned short* __restrict__ xb,   // [16384][4096] bf16
    const unsigned short* __restrict__ Wb,   // [4096][4096]  bf16
    const unsigned short* __restrict__ Tm,   // [16384][32]   bf16 (mask+scale)
    const unsigned short* __restrict__ Bwb,  // [4096][32]    bf16
    const float* __restrict__ bias,          // [4096]
    float* __restrict__ out)                 // [16384][4096] f32
{
  constexpr int K = 4096;
  extern __shared__ char smem[];             // 128 KiB

  const int bid = blockIdx.x;
  const int swz = (bid & 7) * 128 + (bid >> 3);
  const int m0 = (swz >> 4) * 256;
  const int n0 = (swz & 15) * 256;

  const int t = threadIdx.x;
  const int l = t & 63, w = t >> 6;
  const int wqr = w >> 2;
  const int pr = (w >> 1) & 1;
  const int pc = w & 1;
  const int lr = l & 15, hi = l >> 4;
  const int lrb2 = (lr >> 2) & 1;
  const int e0 = hi * 8 + lrb2 * 32;         // phys chunk = logical ^ (lrb2<<2)

  // staging: thread t -> linear LDS 16B chunk t of a 16KB half (row=t>>3,
  // chunk=t&7); source chunk = (t&7) ^ ((row>>2)&1)<<2, row bit2 = t bit5.
  const int srow = t >> 3;
  const int schunk = ((t & 7) ^ (((t >> 5) & 1) << 2)) * 8;
  const unsigned short* pA0 = xb + (size_t)(m0 + srow) * K + schunk;
  const unsigned short* pA1 = xb + (size_t)(m0 + 128 + srow) * K + schunk;
  const unsigned short* pB0 = Wb + (size_t)(n0 + srow) * K + schunk;
  const unsigned short* pB1 = Wb + (size_t)(n0 + 128 + srow) * K + schunk;
  unsigned short* sm = (unsigned short*)smem;
  const int ldst = t * 16;

#define STG(PTR, SLOT, ISB, HALF, KT)                                           \
  do {                                                                          \
    const unsigned short* g_ = (PTR) + (KT) * 64;                               \
    char* d_ = smem + (SLOT) * 65536 + (ISB) * 32768 + (HALF) * 16384 + ldst;   \
    GLOAD_LDS16(g_, d_);                                                        \
    GLOAD_LDS16(g_ + (size_t)64 * K, d_ + 8192);                                \
  } while (0)

  f32x4 acc[2][4][4];
  short8 afr[4];   // persists across the qc1 phase (A reuse)

  // --- LoRA prestep: register-direct (L2-resident), initializes acc ---
  {
    const unsigned short* tp = Tm + (size_t)(m0 + wqr * 128 + pr * 64 + lr) * 32 + hi * 8;
    short8 la[4];
#pragma unroll
    for (int i = 0; i < 4; ++i) la[i] = *(const short8*)(tp + i * 512);
    short8 lb[2][4];
#pragma unroll
    for (int qc = 0; qc < 2; ++qc)
#pragma unroll
      for (int j = 0; j < 4; ++j)
        lb[qc][j] = *(const short8*)(Bwb + (size_t)(n0 + qc * 128 + pc * 64 + j * 16 + lr) * 32 + hi * 8);
#pragma unroll
    for (int qc = 0; qc < 2; ++qc)
#pragma unroll
      for (int i = 0; i < 4; ++i)
#pragma unroll
        for (int j = 0; j < 4; ++j)
          acc[qc][i][j] = __builtin_amdgcn_mfma_f32_16x16x32_bf16(
              la[i], lb[qc][j], (f32x4){0.f, 0.f, 0.f, 0.f}, 0, 0, 0);
  }

  // prologue: s0 all 4 halves @kt0, s1.B0 @kt1
  STG(pA0, 0, 0, 0, 0);
  STG(pA1, 0, 0, 1, 0);
  STG(pB0, 0, 1, 0, 0);
  STG(pB1, 0, 1, 1, 0);
  STG(pB0, 1, 1, 0, 1);
  VMC(2);
  SBAR();

  // READA phases load afr (A@kk) + bfr(B0); non-READA phases load bfr(B1) only.
#define PHASE(SLOT, QC, KK, READA, STG_STMT, WAIT_STMT)                         \
  {                                                                             \
    const unsigned short* Ah = sm + (SLOT) * 32768 + wqr * 8192;                \
    const unsigned short* Bh = sm + (SLOT) * 32768 + 16384 + (QC) * 8192;       \
    const int ek = e0 ^ ((KK) * 32);                                            \
    if (READA) {                                                                \
      _Pragma("unroll")                                                         \
      for (int i = 0; i < 4; ++i)                                               \
        afr[i] = *(const short8*)(Ah + (pr * 64 + i * 16 + lr) * 64 + ek);      \
    }                                                                           \
    short8 bfr[4];                                                              \
    _Pragma("unroll")                                                           \
    for (int j = 0; j < 4; ++j)                                                 \
      bfr[j] = *(const short8*)(Bh + (pc * 64 + j * 16 + lr) * 64 + ek);        \
    STG_STMT;                                                                   \
    SBAR();                                                                     \
    __builtin_amdgcn_s_setprio(1);                                              \
    _Pragma("unroll")                                                           \
    for (int i = 0; i < 4; ++i)                                                 \
      _Pragma("unroll")                                                         \
      for (int j = 0; j < 4; ++j)                                               \
        acc[QC][i][j] = __builtin_amdgcn_mfma_f32_16x16x32_bf16(                \
            afr[i], bfr[j], acc[QC][i][j], 0, 0, 0);                            \
    __builtin_amdgcn_s_setprio(0);                                              \
    WAIT_STMT;                                                                  \
    SBAR();                                                                     \
  }

  // Residency audit (vmcnt(4) = 2 newest halves may fly; queue retires in order):
  //  P0 reads s0.A(prev P4/P5), s0.B0(prev P3)  -> forced landed by prev-P7 VMC(4)
  //  P1 reads s0.B1(prev P6)                    -> landed by P0-end VMC(4)
  //  P4 reads s1.A(P0/P1), s1.B0(prev P7)       -> landed by P3-end VMC(4)
  //  P5 reads s1.B1(P2)                         -> landed by P4-end VMC(4)
  // WAR audit: each STG targets a half whose last read is in an earlier phase.
  for (int I = 0; I < 31; ++I) {
    const int a = 2 * I;
    PHASE(0, 0, 0, 1, STG(pA0, 1, 0, 0, a + 1), VMC(4));
    PHASE(0, 1, 0, 0, STG(pA1, 1, 0, 1, a + 1), VMC(4));
    PHASE(0, 0, 1, 1, STG(pB1, 1, 1, 1, a + 1), VMC(4));
    PHASE(0, 1, 1, 0, STG(pB0, 0, 1, 0, a + 2), VMC(4));
    PHASE(1, 0, 0, 1, STG(pA0, 0, 0, 0, a + 2), VMC(4));
    PHASE(1, 1, 0, 0, STG(pA1, 0, 0, 1, a + 2), VMC(4));
    PHASE(1, 0, 1, 1, STG(pB1, 0, 1, 1, a + 2), VMC(4));
    PHASE(1, 1, 1, 0, STG(pB0, 1, 1, 0, a + 3), VMC(4));
  }
  // tail: a=62, b=63; stage only s1@63 remnants, then drain 4->2->0
  PHASE(0, 0, 0, 1, STG(pA0, 1, 0, 0, 63), VMC(4));
  PHASE(0, 1, 0, 0, STG(pA1, 1, 0, 1, 63), VMC(4));
  PHASE(0, 0, 1, 1, STG(pB1, 1, 1, 1, 63), VMC(4));
  PHASE(0, 1, 1, 0, ((void)0), VMC(2));
  PHASE(1, 0, 0, 1, ((void)0), VMC(0));
  PHASE(1, 1, 0, 0, ((void)0), ((void)0));
  PHASE(1, 0, 1, 1, ((void)0), ((void)0));
  PHASE(1, 1, 1, 0, ((void)0), ((void)0));
#undef PHASE
#undef STG

  // epilogue: bias + store (C/D map: col=lr -> N, row=hi*4+e -> M)
  float bv[2][4];
#pragma unroll
  for (int qc = 0; qc < 2; ++qc)
#pragma unroll
    for (int j = 0; j < 4; ++j)
      bv[qc][j] = bias[n0 + qc * 128 + pc * 64 + j * 16 + lr];
  const int rowb = hi * 4;
#pragma unroll
  for (int qc = 0; qc < 2; ++qc)
#pragma unroll
    for (int i = 0; i < 4; ++i)
#pragma unroll
      for (int e = 0; e < 4; ++e) {
        int row = m0 + wqr * 128 + pr * 64 + i * 16 + rowb + e;
        float* orow = out + (size_t)row * 4096 + n0 + qc * 128 + pc * 64;
#pragma unroll
        for (int j = 0; j < 4; ++j) orow[j * 16 + lr] = acc[qc][i][j][e] + bv[qc][j];
      }
}

// ----------------------------------------------------------------- launch ----
extern "C" void kernel_launch(void* const* d_in, const int* in_sizes, int n_in,
                              void* d_out, int out_size, void* d_ws, size_t ws_size,
                              hipStream_t stream) {
  const float* x   = (const float*)d_in[0];
  const int* offs  = (const int*)d_in[1];
  const float* W   = (const float*)d_in[2];
  const float* b   = (const float*)d_in[3];
  const float* A   = (const float*)d_in[4];
  const float* Bw  = (const float*)d_in[5];
  float* out = (float*)d_out;

  char* ws = (char*)d_ws;
  unsigned short* xb  = (unsigned short*)ws;
  unsigned short* Wb  = (unsigned short*)(ws + 134217728);
  unsigned short* Ab  = (unsigned short*)(ws + 167772160);
  unsigned short* Bwb = (unsigned short*)(ws + 168034304);
  unsigned short* T   = (unsigned short*)(ws + 168296448);

  hipFuncSetAttribute((const void*)gemm_kernel,
                      hipFuncAttributeMaxDynamicSharedMemorySize, 131072);

  cvt_f32_bf16<<<2048, 256, 0, stream>>>(x, xb, 67108864 / 8);
  cvt_f32_bf16<<<2048, 256, 0, stream>>>(W, Wb, 16777216 / 8);
  cvt_f32_bf16<<<64, 256, 0, stream>>>(A, Ab, 131072 / 8);
  cvt_f32_bf16<<<64, 256, 0, stream>>>(Bw, Bwb, 131072 / 8);
  lora_t_kernel<<<256, 256, 0, stream>>>(xb, Ab, offs, T);
  gemm_kernel<<<1024, 512, 131072, stream>>>(xb, Wb, T, Bwb, b, out);
}

// Round 6
// 604.361 us; speedup vs baseline: 1.1233x; 1.0464x over previous
//
#include <hip/hip_runtime.h>
#include <hip/hip_bf16.h>

typedef __attribute__((ext_vector_type(8))) short short8;
typedef __attribute__((ext_vector_type(4))) float f32x4;

#define GLOAD_LDS16(gp, lp)                                                      \
  __builtin_amdgcn_global_load_lds(                                              \
      (const __attribute__((address_space(1))) void*)(gp),                       \
      (__attribute__((address_space(3))) void*)(lp), 16, 0, 0)

#define SBAR() asm volatile("s_barrier" ::: "memory")
#define VMC(n)                                                                   \
  do {                                                                           \
    asm volatile("s_waitcnt vmcnt(" #n ")" ::: "memory");                        \
    __builtin_amdgcn_sched_barrier(0);                                           \
  } while (0)

__device__ __forceinline__ unsigned short f2bf_rne(float f) {
  union { float f; unsigned int u; } v; v.f = f;
  unsigned int u = v.u;
  u += 0x7fffu + ((u >> 16) & 1u);
  return (unsigned short)(u >> 16);
}

// ---------------------------------------------------------------- convert ----
__global__ void cvt_f32_bf16(const float* __restrict__ src,
                             unsigned short* __restrict__ dst, int n8) {
  int i = blockIdx.x * blockDim.x + threadIdx.x;
  int stride = gridDim.x * blockDim.x;
  const f32x4* s4 = (const f32x4*)src;
  short8* d8 = (short8*)dst;
  for (; i < n8; i += stride) {
    f32x4 a = s4[2 * i], b = s4[2 * i + 1];
    short8 o;
    o[0] = (short)f2bf_rne(a[0]); o[1] = (short)f2bf_rne(a[1]);
    o[2] = (short)f2bf_rne(a[2]); o[3] = (short)f2bf_rne(a[3]);
    o[4] = (short)f2bf_rne(b[0]); o[5] = (short)f2bf_rne(b[1]);
    o[6] = (short)f2bf_rne(b[2]); o[7] = (short)f2bf_rne(b[3]);
    d8[i] = o;
  }
}

// ------------------------------------------------- T = mask * 2 * (x @ A^T) ---
__global__ __launch_bounds__(256) void lora_t_kernel(
    const unsigned short* __restrict__ xb,
    const unsigned short* __restrict__ Ab,
    const int* __restrict__ offs,
    unsigned short* __restrict__ T)
{
  __shared__ unsigned short xs[64 * 64];
  __shared__ unsigned short as_[32 * 64];
  const int t = threadIdx.x;
  const int m0 = blockIdx.x * 64;
  const int l = t & 63, w = t >> 6;
  const int lr = l & 15, lk = (l >> 4) * 8;
  const int arow = t >> 3, acol = (t & 7) * 8;
  f32x4 acc0 = {0, 0, 0, 0}, acc1 = {0, 0, 0, 0};
  for (int kt = 0; kt < 64; ++kt) {
    __syncthreads();
    const int kof = kt * 64 + acol;
    GLOAD_LDS16(xb + (size_t)(m0 + arow) * 4096 + kof,      (char*)xs + (arow * 64 + acol) * 2);
    GLOAD_LDS16(xb + (size_t)(m0 + 32 + arow) * 4096 + kof, (char*)xs + ((32 + arow) * 64 + acol) * 2);
    GLOAD_LDS16(Ab + (size_t)arow * 4096 + kof,             (char*)as_ + (arow * 64 + acol) * 2);
    __syncthreads();
#pragma unroll
    for (int kk = 0; kk < 2; ++kk) {
      short8 a  = *(const short8*)&xs[(w * 16 + lr) * 64 + kk * 32 + lk];
      short8 b0 = *(const short8*)&as_[lr * 64 + kk * 32 + lk];
      short8 b1 = *(const short8*)&as_[(16 + lr) * 64 + kk * 32 + lk];
      acc0 = __builtin_amdgcn_mfma_f32_16x16x32_bf16(a, b0, acc0, 0, 0, 0);
      acc1 = __builtin_amdgcn_mfma_f32_16x16x32_bf16(a, b1, acc1, 0, 0, 0);
    }
  }
  const int rowb = (l >> 4) * 4;
#pragma unroll
  for (int j = 0; j < 4; ++j) {
    int m = m0 + w * 16 + rowb + j;
    int bb = m >> 12, s = m & 4095;
    int kcut = offs[bb]; if (kcut > 4096) kcut = 4096;
    bool keep = s >= 4096 - kcut;
    T[(size_t)m * 32 + lr]      = keep ? f2bf_rne(2.0f * acc0[j]) : (unsigned short)0;
    T[(size_t)m * 32 + 16 + lr] = keep ? f2bf_rne(2.0f * acc1[j]) : (unsigned short)0;
  }
}

// ------------------------------------------------------------- main GEMM -----
// 256x256 tile, BK=64, 2 LDS slots x {A,B} x 2 halves (128 rows x 64 els, 16KB).
// 8 waves (wqr = A-half, pr = 64-row sub, pc = 64-col sub); acc[qc][4][4].
// Phases per slot: (qc0,kk0)[A+B0], (qc1,kk0)[B1], (qc0,kk1)[A+B0], (qc1,kk1)[B1]
// -> 24 b128 reads / 64 MFMA / K-tile.
// QUARTER-WAVE swizzle: phys 16B-chunk = logical ^ (row & 7).  Within each
// fixed-lane quarter-wave (hi const, rows base+lr), the 16 lanes cover all 8
// chunk positions exactly twice = 8 words/bank floor.  Rule #21: linear
// gload_lds dest + inverse-permuted global source + same XOR on reads.
__global__ __launch_bounds__(512, 2) void gemm_kernel(
    const unsigned short* __restrict__ xb,   // [16384][4096] bf16
    const unsigned short* __restrict__ Wb,   // [4096][4096]  bf16
    const unsigned short* __restrict__ Tm,   // [16384][32]   bf16 (mask+scale)
    const unsigned short* __restrict__ Bwb,  // [4096][32]    bf16
    const float* __restrict__ bias,          // [4096]
    float* __restrict__ out)                 // [16384][4096] f32
{
  constexpr int K = 4096;
  extern __shared__ char smem[];             // 128 KiB

  const int bid = blockIdx.x;
  const int swz = (bid & 7) * 128 + (bid >> 3);
  const int m0 = (swz >> 4) * 256;
  const int n0 = (swz & 15) * 256;

  const int t = threadIdx.x;
  const int l = t & 63, w = t >> 6;
  const int wqr = w >> 2;
  const int pr = (w >> 1) & 1;
  const int pc = w & 1;
  const int lr = l & 15, hi = l >> 4;
  // read-side swizzle: fragment rows = base16 + lr -> row&7 = lr&7.
  // phys chunk (kk=0) = hi ^ (lr&7); kk=1 flips chunk bit 2 (hi^4 == hi+4).
  const int e0 = (hi ^ (lr & 7)) * 8;

  // staging: thread t -> linear LDS 16B chunk (row=t>>3, c=t&7); source chunk
  // = c ^ (row&7) = (t&7)^((t>>3)&7).  Second 64-row sub-stage: row&7 identical.
  const int srow = t >> 3;
  const int schunk = ((t & 7) ^ ((t >> 3) & 7)) * 8;
  const unsigned short* pA0 = xb + (size_t)(m0 + srow) * K + schunk;
  const unsigned short* pA1 = xb + (size_t)(m0 + 128 + srow) * K + schunk;
  const unsigned short* pB0 = Wb + (size_t)(n0 + srow) * K + schunk;
  const unsigned short* pB1 = Wb + (size_t)(n0 + 128 + srow) * K + schunk;
  unsigned short* sm = (unsigned short*)smem;
  const int ldst = t * 16;

#define STG(PTR, SLOT, ISB, HALF, KT)                                           \
  do {                                                                          \
    const unsigned short* g_ = (PTR) + (KT) * 64;                               \
    char* d_ = smem + (SLOT) * 65536 + (ISB) * 32768 + (HALF) * 16384 + ldst;   \
    GLOAD_LDS16(g_, d_);                                                        \
    GLOAD_LDS16(g_ + (size_t)64 * K, d_ + 8192);                                \
  } while (0)

  f32x4 acc[2][4][4];
  short8 afr[4];   // persists across the qc1 phase (A reuse)

  // --- LoRA prestep: register-direct (L2-resident), initializes acc ---
  {
    const unsigned short* tp = Tm + (size_t)(m0 + wqr * 128 + pr * 64 + lr) * 32 + hi * 8;
    short8 la[4];
#pragma unroll
    for (int i = 0; i < 4; ++i) la[i] = *(const short8*)(tp + i * 512);
    short8 lb[2][4];
#pragma unroll
    for (int qc = 0; qc < 2; ++qc)
#pragma unroll
      for (int j = 0; j < 4; ++j)
        lb[qc][j] = *(const short8*)(Bwb + (size_t)(n0 + qc * 128 + pc * 64 + j * 16 + lr) * 32 + hi * 8);
#pragma unroll
    for (int qc = 0; qc < 2; ++qc)
#pragma unroll
      for (int i = 0; i < 4; ++i)
#pragma unroll
        for (int j = 0; j < 4; ++j)
          acc[qc][i][j] = __builtin_amdgcn_mfma_f32_16x16x32_bf16(
              la[i], lb[qc][j], (f32x4){0.f, 0.f, 0.f, 0.f}, 0, 0, 0);
  }

  // prologue: s0 all 4 halves @kt0, s1.B0 @kt1
  STG(pA0, 0, 0, 0, 0);
  STG(pA1, 0, 0, 1, 0);
  STG(pB0, 0, 1, 0, 0);
  STG(pB1, 0, 1, 1, 0);
  STG(pB0, 1, 1, 0, 1);
  VMC(2);
  SBAR();

  // READA phases load afr (A@kk) + bfr(B0); non-READA phases load bfr(B1) only.
#define PHASE(SLOT, QC, KK, READA, STG_STMT, WAIT_STMT)                         \
  {                                                                             \
    const unsigned short* Ah = sm + (SLOT) * 32768 + wqr * 8192;                \
    const unsigned short* Bh = sm + (SLOT) * 32768 + 16384 + (QC) * 8192;       \
    const int ek = e0 ^ ((KK) * 32);                                            \
    if (READA) {                                                                \
      _Pragma("unroll")                                                         \
      for (int i = 0; i < 4; ++i)                                               \
        afr[i] = *(const short8*)(Ah + (pr * 64 + i * 16 + lr) * 64 + ek);      \
    }                                                                           \
    short8 bfr[4];                                                              \
    _Pragma("unroll")                                                           \
    for (int j = 0; j < 4; ++j)                                                 \
      bfr[j] = *(const short8*)(Bh + (pc * 64 + j * 16 + lr) * 64 + ek);        \
    STG_STMT;                                                                   \
    SBAR();                                                                     \
    __builtin_amdgcn_s_setprio(1);                                              \
    _Pragma("unroll")                                                           \
    for (int i = 0; i < 4; ++i)                                                 \
      _Pragma("unroll")                                                         \
      for (int j = 0; j < 4; ++j)                                               \
        acc[QC][i][j] = __builtin_amdgcn_mfma_f32_16x16x32_bf16(                \
            afr[i], bfr[j], acc[QC][i][j], 0, 0, 0);                            \
    __builtin_amdgcn_s_setprio(0);                                              \
    WAIT_STMT;                                                                  \
    SBAR();                                                                     \
  }

  // Residency audit (vmcnt(4) = 2 newest halves may fly; queue retires in order):
  //  P0 reads s0.A(prev P4/P5), s0.B0(prev P3)  -> forced landed by prev-P7 VMC(4)
  //  P1 reads s0.B1(prev P6)                    -> landed by P0-end VMC(4)
  //  P4 reads s1.A(P0/P1), s1.B0(prev P7)       -> landed by P3-end VMC(4)
  //  P5 reads s1.B1(P2)                         -> landed by P4-end VMC(4)
  // WAR audit: each STG targets a half whose last read is in an earlier phase.
  for (int I = 0; I < 31; ++I) {
    const int a = 2 * I;
    PHASE(0, 0, 0, 1, STG(pA0, 1, 0, 0, a + 1), VMC(4));
    PHASE(0, 1, 0, 0, STG(pA1, 1, 0, 1, a + 1), VMC(4));
    PHASE(0, 0, 1, 1, STG(pB1, 1, 1, 1, a + 1), VMC(4));
    PHASE(0, 1, 1, 0, STG(pB0, 0, 1, 0, a + 2), VMC(4));
    PHASE(1, 0, 0, 1, STG(pA0, 0, 0, 0, a + 2), VMC(4));
    PHASE(1, 1, 0, 0, STG(pA1, 0, 0, 1, a + 2), VMC(4));
    PHASE(1, 0, 1, 1, STG(pB1, 0, 1, 1, a + 2), VMC(4));
    PHASE(1, 1, 1, 0, STG(pB0, 1, 1, 0, a + 3), VMC(4));
  }
  // tail: a=62, b=63; stage only s1@63 remnants, then drain 4->2->0
  PHASE(0, 0, 0, 1, STG(pA0, 1, 0, 0, 63), VMC(4));
  PHASE(0, 1, 0, 0, STG(pA1, 1, 0, 1, 63), VMC(4));
  PHASE(0, 0, 1, 1, STG(pB1, 1, 1, 1, 63), VMC(4));
  PHASE(0, 1, 1, 0, ((void)0), VMC(2));
  PHASE(1, 0, 0, 1, ((void)0), VMC(0));
  PHASE(1, 1, 0, 0, ((void)0), ((void)0));
  PHASE(1, 0, 1, 1, ((void)0), ((void)0));
  PHASE(1, 1, 1, 0, ((void)0), ((void)0));
#undef PHASE
#undef STG

  // epilogue: bias + store (C/D map: col=lr -> N, row=hi*4+e -> M)
  float bv[2][4];
#pragma unroll
  for (int qc = 0; qc < 2; ++qc)
#pragma unroll
    for (int j = 0; j < 4; ++j)
      bv[qc][j] = bias[n0 + qc * 128 + pc * 64 + j * 16 + lr];
  const int rowb = hi * 4;
#pragma unroll
  for (int qc = 0; qc < 2; ++qc)
#pragma unroll
    for (int i = 0; i < 4; ++i)
#pragma unroll
      for (int e = 0; e < 4; ++e) {
        int row = m0 + wqr * 128 + pr * 64 + i * 16 + rowb + e;
        float* orow = out + (size_t)row * 4096 + n0 + qc * 128 + pc * 64;
#pragma unroll
        for (int j = 0; j < 4; ++j) orow[j * 16 + lr] = acc[qc][i][j][e] + bv[qc][j];
      }
}

// ----------------------------------------------------------------- launch ----
extern "C" void kernel_launch(void* const* d_in, const int* in_sizes, int n_in,
                              void* d_out, int out_size, void* d_ws, size_t ws_size,
                              hipStream_t stream) {
  const float* x   = (const float*)d_in[0];
  const int* offs  = (const int*)d_in[1];
  const float* W   = (const float*)d_in[2];
  const float* b   = (const float*)d_in[3];
  const float* A   = (const float*)d_in[4];
  const float* Bw  = (const float*)d_in[5];
  float* out = (float*)d_out;

  char* ws = (char*)d_ws;
  unsigned short* xb  = (unsigned short*)ws;
  unsigned short* Wb  = (unsigned short*)(ws + 134217728);
  unsigned short* Ab  = (unsigned short*)(ws + 167772160);
  unsigned short* Bwb = (unsigned short*)(ws + 168034304);
  unsigned short* T   = (unsigned short*)(ws + 168296448);

  hipFuncSetAttribute((const void*)gemm_kernel,
                      hipFuncAttributeMaxDynamicSharedMemorySize, 131072);

  cvt_f32_bf16<<<2048, 256, 0, stream>>>(x, xb, 67108864 / 8);
  cvt_f32_bf16<<<2048, 256, 0, stream>>>(W, Wb, 16777216 / 8);
  cvt_f32_bf16<<<64, 256, 0, stream>>>(A, Ab, 131072 / 8);
  cvt_f32_bf16<<<64, 256, 0, stream>>>(Bw, Bwb, 131072 / 8);
  lora_t_kernel<<<256, 256, 0, stream>>>(xb, Ab, offs, T);
  gemm_kernel<<<1024, 512, 131072, stream>>>(xb, Wb, T, Bwb, b, out);
}